// Round 1
// baseline (4428.707 us; speedup 1.0000x reference)
//
#include <hip/hip_runtime.h>
#include <cstdint>
#include <cstddef>

#define NFILT 40
#define NBINS 257
#define HID   64
#define BB    64      // batch
#define TT    2000    // time
#define GATES 256     // 4*HID
#define MTOT  (BB*TT) // 128000 rows

// ---------- activations ----------
__device__ __forceinline__ float sigm(float x) {
  return 1.0f / (1.0f + __expf(-x));
}
__device__ __forceinline__ float tanh_(float x) {
  float e = __expf(-2.0f * fabsf(x));
  float r = (1.0f - e) / (1.0f + e);
  return copysignf(r, x);
}

// ---------- kernel 1: build fbank (40x257) + per-filter support bounds ----------
__global__ void k_fbank(const float* __restrict__ binpoints,
                        float* __restrict__ fbank,
                        int* __restrict__ lohi /*[2*NFILT]*/) {
  __shared__ float b[NFILT + 2];
  int tid = threadIdx.x;
  if (tid < NFILT + 2) b[tid] = binpoints[tid];
  __syncthreads();
  if (tid < NFILT) {
    if (tid == NFILT - 1) { lohi[tid] = 0; lohi[NFILT + tid] = 0; }
    else {
      int lo = (int)floorf(b[tid]);
      int hi = (int)floorf(b[tid + 2]);
      if (lo < 0) lo = 0;
      if (hi > NBINS) hi = NBINS;
      lohi[tid] = lo; lohi[NFILT + tid] = hi;
    }
  }
  for (int idx = tid; idx < NFILT * NBINS; idx += blockDim.x) {
    int f = idx / NBINS, i = idx - f * NBINS;
    float bj = b[f], bj1 = b[f + 1], bj2 = b[f + 2];
    float fb0 = floorf(bj), fb1 = floorf(bj1), fb2 = floorf(bj2);
    float fi = (float)i;
    bool rise = (fi >= fb0) && (fi < fb1);
    bool fall = (fi >= fb1) && (fi < fb2);
    float d1 = bj1 - bj;  d1 = (d1 > 0.f) ? d1 : 1.f;
    float d2 = bj2 - bj1; d2 = (d2 > 0.f) ? d2 : 1.f;
    float rv = (fi - bj)  / (d1 * d1);
    float fv = (bj2 - fi) / (d2 * d2);
    float v = fall ? fv : (rise ? rv : 0.f);
    if (f == NFILT - 1) v = 0.f;
    fbank[idx] = v;
  }
}

// ---------- kernel 2: featurize  h0[bt][f] = log(filt + 1e-10) ----------
__global__ __launch_bounds__(64) void k_feat(const float* __restrict__ x,
                                             const float* __restrict__ fbank,
                                             const int* __restrict__ lohi,
                                             float* __restrict__ h0) {
  int bt = blockIdx.x;
  __shared__ float xs[NBINS];
  const float* xr = x + (size_t)bt * NBINS;
  for (int i = threadIdx.x; i < NBINS; i += 64) xs[i] = xr[i];
  __syncthreads();
  int f = threadIdx.x;
  if (f < NFILT) {
    float acc = 0.f;
    int lo = lohi[f], hi = lohi[NFILT + f];
    for (int i = lo; i < hi; ++i) acc = fmaf(xs[i], fbank[f * NBINS + i], acc);
    float val = (f == 0) ? xs[0] : acc;
    h0[(size_t)bt * NFILT + f] = logf(val + 1e-10f);
  }
}

// ---------- kernel 3: fp32 GEMM  pre[d][m][g] = H[m][:]·W[d][g][:] + bih[d][g] + bhh[d][g] ----------
template <int K, int BK>
__global__ __launch_bounds__(256) void k_gemm(const float* __restrict__ Hm,   // [MTOT][K]
                                              const float* __restrict__ W,    // [2][256][K]
                                              const float* __restrict__ bih,  // [2][256]
                                              const float* __restrict__ bhh,  // [2][256]
                                              float* __restrict__ pre) {      // [2][MTOT][256]
  constexpr int BM = 128, BN = 64;
  __shared__ float Hs[BK][BM + 4];
  __shared__ float Ws[BK][BN + 4];
  const int d  = blockIdx.z;
  const int m0 = blockIdx.x * BM;
  const int g0 = blockIdx.y * BN;
  const int tid = threadIdx.x;
  const int tx = tid & 15, ty = tid >> 4;

  float acc[8][4];
#pragma unroll
  for (int r = 0; r < 8; ++r)
#pragma unroll
    for (int j = 0; j < 4; ++j) acc[r][j] = 0.f;

  for (int k0 = 0; k0 < K; k0 += BK) {
    constexpr int HL = BM * BK / 256;
#pragma unroll
    for (int i = 0; i < HL; ++i) {
      int flat = tid + i * 256;
      int r = flat / BK, kk = flat - r * BK;
      Hs[kk][r] = Hm[(size_t)(m0 + r) * K + k0 + kk];
    }
    constexpr int WL = BN * BK / 256;
#pragma unroll
    for (int i = 0; i < WL; ++i) {
      int flat = tid + i * 256;
      int r = flat / BK, kk = flat - r * BK;
      Ws[kk][r] = W[((size_t)d * GATES + g0 + r) * K + k0 + kk];
    }
    __syncthreads();
#pragma unroll
    for (int kk = 0; kk < BK; ++kk) {
      const float4 wv  = *(const float4*)&Ws[kk][tx * 4];
      const float4 hv0 = *(const float4*)&Hs[kk][ty * 8];
      const float4 hv1 = *(const float4*)&Hs[kk][ty * 8 + 4];
      const float hr[8] = {hv0.x, hv0.y, hv0.z, hv0.w, hv1.x, hv1.y, hv1.z, hv1.w};
#pragma unroll
      for (int r = 0; r < 8; ++r) {
        acc[r][0] = fmaf(hr[r], wv.x, acc[r][0]);
        acc[r][1] = fmaf(hr[r], wv.y, acc[r][1]);
        acc[r][2] = fmaf(hr[r], wv.z, acc[r][2]);
        acc[r][3] = fmaf(hr[r], wv.w, acc[r][3]);
      }
    }
    __syncthreads();
  }

  const int gcol = g0 + tx * 4;
  const float4 bi = *(const float4*)&bih[d * GATES + gcol];
  const float4 bh = *(const float4*)&bhh[d * GATES + gcol];
  const float bx = bi.x + bh.x, by = bi.y + bh.y, bz = bi.z + bh.z, bw = bi.w + bh.w;
#pragma unroll
  for (int r = 0; r < 8; ++r) {
    size_t m = (size_t)(m0 + ty * 8 + r);
    float4 o = {acc[r][0] + bx, acc[r][1] + by, acc[r][2] + bz, acc[r][3] + bw};
    *(float4*)&pre[((size_t)d * MTOT + m) * GATES + gcol] = o;
  }
}

// ---------- kernel 4: recurrent LSTM, one block per (batch, dir) ----------
__global__ __launch_bounds__(256) void k_lstm(const float* __restrict__ pre, // [2][B*T][256]
                                              const float* __restrict__ whh, // [2][256][64]
                                              float* __restrict__ hout,      // [B][T][128]
                                              float* __restrict__ out,       // [B][128]
                                              int final_layer) {
  const int b = blockIdx.x, d = blockIdx.y;
  const int g = threadIdx.x;
  __shared__ __align__(16) float h_s[HID];
  __shared__ float gate_s[GATES];

  float w[HID];
  const float* wr = whh + ((size_t)d * GATES + g) * HID;
#pragma unroll
  for (int k = 0; k < HID; k += 4) {
    const float4 t4 = *(const float4*)&wr[k];
    w[k] = t4.x; w[k + 1] = t4.y; w[k + 2] = t4.z; w[k + 3] = t4.w;
  }
  if (g < HID) h_s[g] = 0.f;
  float c = 0.f, sum = 0.f;
  __syncthreads();

  const size_t base = ((size_t)d * BB + b) * (size_t)TT;
  const int t0 = d ? (TT - 1) : 0;
  const int dt = d ? -1 : 1;

  float pc = pre[(base + t0) * (size_t)GATES + g];
  float pn = pre[(base + t0 + dt) * (size_t)GATES + g];

  for (int t = 0; t < TT; ++t) {
    const int ta = t0 + dt * t;
    float pn2 = 0.f;
    if (t + 2 < TT) pn2 = pre[(base + ta + 2 * dt) * (size_t)GATES + g];

    float a0 = 0.f, a1 = 0.f, a2 = 0.f, a3 = 0.f;
    const float4* h4 = (const float4*)h_s;
#pragma unroll
    for (int kk = 0; kk < HID / 4; ++kk) {
      const float4 hv = h4[kk];
      a0 = fmaf(hv.x, w[4 * kk + 0], a0);
      a1 = fmaf(hv.y, w[4 * kk + 1], a1);
      a2 = fmaf(hv.z, w[4 * kk + 2], a2);
      a3 = fmaf(hv.w, w[4 * kk + 3], a3);
    }
    const float z = ((a0 + a1) + (a2 + a3)) + pc;
    const int gt = g >> 6;                       // wave-uniform
    const float val = (gt == 2) ? tanh_(z) : sigm(z);
    gate_s[g] = val;
    __syncthreads();
    if (g < HID) {
      const float ig = gate_s[g], fg = gate_s[HID + g];
      const float gg = gate_s[2 * HID + g], og = gate_s[3 * HID + g];
      c = fg * c + ig * gg;
      const float hv = og * tanh_(c);
      h_s[g] = hv;
      if (final_layer) sum += hv;
      else hout[((size_t)b * TT + ta) * (2 * HID) + d * HID + g] = hv;
    }
    __syncthreads();
    pc = pn; pn = pn2;
  }
  if (final_layer && g < HID) out[b * (2 * HID) + d * HID + g] = sum * (1.0f / (float)TT);
}

// ---------- launch ----------
extern "C" void kernel_launch(void* const* d_in, const int* in_sizes, int n_in,
                              void* d_out, int out_size, void* d_ws, size_t ws_size,
                              hipStream_t stream) {
  const float* x         = (const float*)d_in[0];
  const float* binpoints = (const float*)d_in[1];
  const float* w_ih[3] = {(const float*)d_in[2], (const float*)d_in[6],  (const float*)d_in[10]};
  const float* w_hh[3] = {(const float*)d_in[3], (const float*)d_in[7],  (const float*)d_in[11]};
  const float* b_ih[3] = {(const float*)d_in[4], (const float*)d_in[8],  (const float*)d_in[12]};
  const float* b_hh[3] = {(const float*)d_in[5], (const float*)d_in[9],  (const float*)d_in[13]};
  float* out = (float*)d_out;

  // workspace layout (needs ~349 MB):
  //   pre  : 2*MTOT*256 f32 = 262,144,000 B
  //   Hbuf : MTOT*128 f32   =  65,536,000 B
  //   h0   : MTOT*40 f32    =  20,480,000 B
  //   fbank: 40*257 f32, lohi: 80 i32
  float* pre   = (float*)d_ws;
  float* Hbuf  = pre  + (size_t)2 * MTOT * GATES;
  float* h0    = Hbuf + (size_t)MTOT * 128;
  float* fbank = h0   + (size_t)MTOT * NFILT;
  int*   lohi  = (int*)(fbank + NFILT * NBINS);

  k_fbank<<<1, 256, 0, stream>>>(binpoints, fbank, lohi);
  k_feat<<<MTOT, 64, 0, stream>>>(x, fbank, lohi, h0);

  // layer 0 (K=40)
  k_gemm<40, 40><<<dim3(MTOT / 128, GATES / 64, 2), 256, 0, stream>>>(h0, w_ih[0], b_ih[0], b_hh[0], pre);
  k_lstm<<<dim3(BB, 2), 256, 0, stream>>>(pre, w_hh[0], Hbuf, out, 0);

  // layer 1 (K=128)
  k_gemm<128, 32><<<dim3(MTOT / 128, GATES / 64, 2), 256, 0, stream>>>(Hbuf, w_ih[1], b_ih[1], b_hh[1], pre);
  k_lstm<<<dim3(BB, 2), 256, 0, stream>>>(pre, w_hh[1], Hbuf, out, 0);

  // layer 2 (K=128)
  k_gemm<128, 32><<<dim3(MTOT / 128, GATES / 64, 2), 256, 0, stream>>>(Hbuf, w_ih[2], b_ih[2], b_hh[2], pre);
  k_lstm<<<dim3(BB, 2), 256, 0, stream>>>(pre, w_hh[2], Hbuf, out, 1);
}